// Round 12
// baseline (289.102 us; speedup 1.0000x reference)
//
#include <hip/hip_runtime.h>
#include <math.h>
#include <limits.h>

// LogPolar resample: data [32,3,512,512] f32 -> out [32,3,512,512] f32.
// R4: 8 XCD-pinned image chunks -> 173us. R6: float2 gathers -> 113us.
// R5/R8/R9: three MLP experiments all defeated by compiler (VGPR stayed 32)
// and all neutral => model re-fit: global divergent gathers cost ~1 cyc/lane
// (64 cyc/wave-instr) in the TA path; cost ~ #gather-instrs, not latency.
// R10/R11: move gathers to LDS (bank-parallel, ~2-10 cyc/instr):
//   - per 16x16 tile: reduce bbox of taps; stage bbox per-image into LDS
//     (coalesced rows, 2-deep pipelined); gather via 2x ds_read2_b32;
//   - lanes remapped 4x16 so stores are 4 FULL 64B lines (write=101MB ideal);
//   - oversized-bbox tiles (Wb>128 or (Hb+1)*S>8192) fall back to R6 global
//     path; fully-OOB tiles store zeros and exit.

constexpr int H_IN  = 512;
constexpr int W_IN  = 512;
constexpr int BC    = 32 * 3;
constexpr int IMG   = H_IN * W_IN;
constexpr int NCHUNK = 8;              // = #XCDs
constexpr int IPC   = BC / NCHUNK;     // 12 images per chunk
constexpr int LDS_FLOATS = 8192;       // 32 KB stage buffer

__device__ __forceinline__ float2 ld2(const float* p) {
    float2 v;
    __builtin_memcpy(&v, p, sizeof(v));
    return v;
}

__global__ __launch_bounds__(256) void logpolar_kernel(
    const float* __restrict__ data, float* __restrict__ out)
{
    __shared__ float smem[LDS_FLOATS];
    __shared__ int red[16];

    const int chunk = blockIdx.x & (NCHUNK - 1);
    const int tile  = blockIdx.x >> 3;            // 1024 tiles of 16x16 px
    const int tile_i = (tile >> 5) << 4;
    const int tile_j = (tile & 31) << 4;

    const int t = threadIdx.x;
    const int w = t >> 6;                          // wave 0..3
    const int l = t & 63;                          // lane
    const int row = t >> 4;                        // 0..15 (4 rows per wave)
    const int col = t & 15;                        // 0..15
    const int i = tile_i + row;                    // theta index
    const int j = tile_j + col;                    // r index
    const int pix = (i << 9) | j;                  // lane0 of each row: 64B-aligned

    // max_r = np.float32(log(norm([512,512])/2 * 2.0)) — f64 value, exact cast.
    const float max_r = (float)6.584898215319481;
    const float theta  = ((float)(2 * i) * 3.14159274101257324f) / 512.0f;
    const float radius = expf(((float)j * max_r) / 512.0f);
    const float X = 256.0f + radius * cosf(theta);
    const float Y = 256.0f - radius * sinf(theta);

    const bool ib =
        (X >= 0.0f) && (X < 512.0f) && (Y >= 0.0f) && (Y < 512.0f);

    // trunc-toward-zero (X,Y >= 0 when ib); OOB lanes get safe dummies.
    const int y_down = ib ? (int)Y : 0;
    const int x_down = ib ? (int)X : 0;
    const int y_up = min(y_down + 1, H_IN - 1);
    const int x_up = min(x_down + 1, W_IN - 1);

    const float yd = Y - (float)y_down;
    const float yu = Y - (float)y_up;
    const float xd = X - (float)x_down;
    const float xu = X - (float)x_up;
    const float dd = yd * yd + xd * xd;
    const float du = yd * yd + xu * xu;
    const float ud = yu * yu + xd * xd;
    const float uu = yu * yu + xu * xu;
    const float total = ((dd + du) + ud) + uu;
    const float wdd = dd / total;
    const float wdu = du / total;
    const float wud = ud / total;
    const float wuu = uu / total;

    // ---- block-wide bbox of taps (in-bounds lanes only) ----
    int ymn = ib ? y_down : INT_MAX;
    int ymx = ib ? y_up   : INT_MIN;
    int xmn = ib ? x_down : INT_MAX;
    int xmx = ib ? x_up   : INT_MIN;
    #pragma unroll
    for (int m = 1; m < 64; m <<= 1) {
        ymn = min(ymn, __shfl_xor(ymn, m));
        ymx = max(ymx, __shfl_xor(ymx, m));
        xmn = min(xmn, __shfl_xor(xmn, m));
        xmx = max(xmx, __shfl_xor(xmx, m));
    }
    if (l == 0) {
        red[w * 4 + 0] = ymn; red[w * 4 + 1] = ymx;
        red[w * 4 + 2] = xmn; red[w * 4 + 3] = xmx;
    }
    __syncthreads();
    ymn = min(min(red[0], red[4]), min(red[8],  red[12]));
    ymx = max(max(red[1], red[5]), max(red[9],  red[13]));
    xmn = min(min(red[2], red[6]), min(red[10], red[14]));
    xmx = max(max(red[3], red[7]), max(red[11], red[15]));

    const float* p = data + (size_t)chunk * IPC * IMG;
    float*       q = out  + (size_t)chunk * IPC * IMG + pix;

    if (ymx == INT_MIN) {                          // whole tile out of bounds
        #pragma unroll
        for (int bc = 0; bc < IPC; ++bc) q[bc * IMG] = 0.0f;
        return;
    }

    const int Hb = ymx - ymn + 1;
    const int Wb = xmx - xmn + 1;
    const bool narrow = (Wb <= 64);
    const int S = narrow ? 65 : 129;               // padded LDS row stride (odd)

    // LDS path requires: columns coverable by 2 staging lanes (Wb <= 128)
    // AND (Hb+1) padded rows fitting the 32KB buffer.
    if (Wb <= 128 && (Hb + 1) * S <= LDS_FLOATS) {
        // ---- LDS-staged path ----
        const int o  = ib ? ((y_down - ymn) * S + (x_down - xmn)) : 0;
        const bool cx = (x_up > x_down);           // no x-clamp aliasing
        const bool cy = (y_up > y_down);           // no y-clamp aliasing
        const int cg0 = xmn + min(l, Wb - 1);      // staging cols (clamped dup)
        const int cg1 = xmn + min(l + 64, Wb - 1);

        for (int bc = 0; bc < IPC; ++bc) {
            const float* img = p + bc * IMG;
            if (narrow) {
                int r = w;
                float v0 = img[(ymn + min(r, Hb - 1)) * 512 + cg0];
                while (r < Hb) {
                    const int rn = r + 4;
                    const float v1 = img[(ymn + min(rn, Hb - 1)) * 512 + cg0];
                    smem[r * 65 + l] = v0;
                    v0 = v1; r = rn;
                }
            } else {
                int r = w;
                int rg = (ymn + min(r, Hb - 1)) * 512;
                float v0 = img[rg + cg0];
                float u0 = img[rg + cg1];
                while (r < Hb) {
                    const int rn = r + 4;
                    rg = (ymn + min(rn, Hb - 1)) * 512;
                    const float v1 = img[rg + cg0];
                    const float u1 = img[rg + cg1];
                    smem[r * 129 + l] = v0;
                    smem[r * 129 + 64 + l] = u0;
                    v0 = v1; u0 = u1; r = rn;
                }
            }
            __syncthreads();
            // 4 taps via 2x ds_read2_b32: {o,o+1} and {o+S,o+S+1}
            const float a0 = smem[o];
            const float a1 = smem[o + 1];
            const float b0 = smem[o + S];
            const float b1 = smem[o + S + 1];
            const float fdu = cx ? a1 : a0;
            const float fud = cy ? b0 : a0;
            const float fuu = cy ? (cx ? b1 : b0) : fdu;
            const float v = ((wdd * a0 + wdu * fdu) + wud * fud) + wuu * fuu;
            q[bc * IMG] = ib ? v : 0.0f;
            __syncthreads();                       // before next image overwrites
        }
    } else {
        // ---- fallback: R6 global float2 gathers (big-bbox outer tiles) ----
        const int o_d = y_down * 512 + x_down;
        const int o_u = y_up   * 512 + x_down;
        if (!ib) {
            #pragma unroll
            for (int bc = 0; bc < IPC; ++bc) q[bc * IMG] = 0.0f;
        } else if (x_up > x_down) {
            #pragma unroll 4
            for (int bc = 0; bc < IPC; ++bc) {
                const float* pp = p + bc * IMG;
                const float2 a = ld2(pp + o_d);
                const float2 b = ld2(pp + o_u);
                q[bc * IMG] = ((wdd * a.x + wdu * a.y) + wud * b.x) + wuu * b.y;
            }
        } else {
            #pragma unroll
            for (int bc = 0; bc < IPC; ++bc) {
                const float* pp = p + bc * IMG;
                const float ga = pp[o_d];
                const float gb = pp[o_u];
                q[bc * IMG] = ((wdd * ga + wdu * ga) + wud * gb) + wuu * gb;
            }
        }
    }
}

extern "C" void kernel_launch(void* const* d_in, const int* in_sizes, int n_in,
                              void* d_out, int out_size, void* d_ws, size_t ws_size,
                              hipStream_t stream)
{
    const float* data = (const float*)d_in[0];
    float* out = (float*)d_out;

    const int threads = 256;                       // 16x16 px tile per block
    const int blocks = (512 / 16) * (512 / 16) * NCHUNK;  // 1024 * 8 = 8192
    logpolar_kernel<<<blocks, threads, 0, stream>>>(data, out);
}